// Round 16
// baseline (334.141 us; speedup 1.0000x reference)
//
#include <hip/hip_runtime.h>
#include <hip/hip_bf16.h>
#include <math.h>

typedef __attribute__((ext_vector_type(8))) short short8;
typedef __attribute__((ext_vector_type(4))) float f32x4;
typedef __attribute__((ext_vector_type(4))) unsigned short ushort4_t;

#define MFMA16(a, b, c) __builtin_amdgcn_mfma_f32_16x16x32_bf16((a), (b), (c), 0, 0, 0)

#define GLOAD_LDS16(src, ldsbase)                                                     \
  __builtin_amdgcn_global_load_lds(                                                   \
      (const __attribute__((address_space(1))) void*)(src),                           \
      (__attribute__((address_space(3))) void*)(ldsbase), 16, 0, 0)

// Native RNE fp32->bf16 (compiler emits v_cvt_pk_bf16_f32 pairs).
static __device__ __forceinline__ unsigned short f2bf(float f) {
  __hip_bfloat16 h = __float2bfloat16(f);
  unsigned short u;
  __builtin_memcpy(&u, &h, 2);
  return u;
}

static __device__ __forceinline__ float bf2f(unsigned short b) {
  union { unsigned u; float f; } v; v.u = ((unsigned)b) << 16;
  return v.f;
}

static __device__ __forceinline__ short8 cvt2v(f32x4 a, f32x4 b) {
  short8 t;
#pragma unroll
  for (int j = 0; j < 4; ++j) t[j] = (short)f2bf(a[j]);
#pragma unroll
  for (int j = 0; j < 4; ++j) t[4 + j] = (short)f2bf(b[j]);
  return t;
}

// Barrier that waits only LDS (lgkmcnt), NOT vmcnt.
static __device__ __forceinline__ void lds_barrier() {
  __builtin_amdgcn_sched_barrier(0);
  asm volatile("s_waitcnt lgkmcnt(0)" ::: "memory");
  __builtin_amdgcn_s_barrier();
  __builtin_amdgcn_sched_barrier(0);
}

// fp32->bf16 weights. wq/wk/wv linear; wo FRAG-MAJOR for the attn epilogue.
__global__ __launch_bounds__(256) void cvt_w(
    const float* __restrict__ wq, const float* __restrict__ wk,
    const float* __restrict__ wv, const float* __restrict__ wo,
    unsigned short* __restrict__ wq16, unsigned short* __restrict__ wk16,
    unsigned short* __restrict__ wv16, unsigned short* __restrict__ wo16) {
  const int blk = blockIdx.x;
  const float* src;
  unsigned short* dst;
  size_t base;
  bool frag = false;
  if (blk < 128)      { src = wq; dst = wq16; base = (size_t)blk * 2048; }
  else if (blk < 256) { src = wk; dst = wk16; base = (size_t)(blk - 128) * 2048; }
  else if (blk < 384) { src = wv; dst = wv16; base = (size_t)(blk - 256) * 2048; }
  else                { src = wo; dst = wo16; base = (size_t)(blk - 384) * 2048; frag = true; }
  const size_t i = base + (size_t)threadIdx.x * 8;
  f32x4 a = *(const f32x4*)(src + i);
  f32x4 b = *(const f32x4*)(src + i + 4);
  if (!frag) {
    *(short8*)(dst + i) = cvt2v(a, b);
  } else {
    const int c = (int)(i >> 9), k = (int)(i & 511);
    size_t addr = (size_t)(c >> 4) * 8192 + (k >> 5) * 512 + ((k >> 3) & 3) * 128 +
                  (c & 15) * 8 + (k & 7);
    *(short8*)(dst + addr) = cvt2v(a, b);
  }
}

// Merged QKV projection, z=0/1/2 (R15 verbatim).
__global__ __launch_bounds__(256) void proj_gemm(
    const float* __restrict__ q, const float* __restrict__ k, const float* __restrict__ v,
    const unsigned short* __restrict__ wq16, const unsigned short* __restrict__ wk16,
    const unsigned short* __restrict__ wv16,
    const float* __restrict__ bq, const float* __restrict__ bk, const float* __restrict__ bv,
    unsigned short* __restrict__ qh, unsigned short* __restrict__ kh,
    unsigned short* __restrict__ vt) {
  __shared__ unsigned short As[128 * 64], Ws[128 * 64];
  const int z = blockIdx.z;
  const float* A = z == 0 ? q : z == 1 ? k : v;
  const unsigned short* W16 = z == 0 ? wq16 : z == 1 ? wk16 : wv16;
  const float* bias = z == 0 ? bq : z == 1 ? bk : bv;
  unsigned short* outp = z == 0 ? qh : z == 1 ? kh : vt;

  const int tid = threadIdx.x;
  const int wv_ = tid >> 6, lane = tid & 63;
  const int lr = lane & 15, lg = lane >> 4;
  const int m0 = blockIdx.x * 128, n0 = blockIdx.y * 128;
  const int wm = (wv_ >> 1) * 64, wn = (wv_ & 1) * 64;

  f32x4 acc[4][4] = {};  // z<2: [ni][mi]; z==2: [mi][ni]

  for (int k0 = 0; k0 < 512; k0 += 64) {
#pragma unroll
    for (int p = 0; p < 4; ++p) {
      const int row = (p * 4 + wv_) * 8 + (lane >> 3);
      const int col = (lane & 7) * 8;
      GLOAD_LDS16(W16 + (size_t)(n0 + row) * 512 + k0 + col, &Ws[(p * 4 + wv_) * 512]);
    }
    const int row = (tid >> 3), col = (tid & 7) * 8;
#pragma unroll
    for (int p = 0; p < 4; ++p) {
      const float* src = A + (size_t)(m0 + p * 32 + row) * 512 + k0 + col;
      f32x4 a0 = *(const f32x4*)src;
      f32x4 a1 = *(const f32x4*)(src + 4);
      *(short8*)&As[(p * 32 + row) * 64 + col] = cvt2v(a0, a1);
    }
    __syncthreads();  // drains vmcnt (gload_lds) + lgkmcnt (ds_write)

#pragma unroll
    for (int ks = 0; ks < 2; ++ks) {
      short8 af[4], bw[4];
#pragma unroll
      for (int mi = 0; mi < 4; ++mi)
        af[mi] = *(const short8*)&As[(wm + mi * 16 + lr) * 64 + ks * 32 + lg * 8];
#pragma unroll
      for (int ni = 0; ni < 4; ++ni)
        bw[ni] = *(const short8*)&Ws[(wn + ni * 16 + lr) * 64 + ks * 32 + lg * 8];
      if (z < 2) {
#pragma unroll
        for (int ni = 0; ni < 4; ++ni)
#pragma unroll
          for (int mi = 0; mi < 4; ++mi)
            acc[ni][mi] = MFMA16(bw[ni], af[mi], acc[ni][mi]);  // swapped
      } else {
#pragma unroll
        for (int mi = 0; mi < 4; ++mi)
#pragma unroll
          for (int ni = 0; ni < 4; ++ni)
            acc[mi][ni] = MFMA16(af[mi], bw[ni], acc[mi][ni]);
      }
    }
    __syncthreads();
  }

  const int hI = (n0 + wn) >> 6;
  if (z < 2) {
#pragma unroll
    for (int ni = 0; ni < 4; ++ni) {
      const int d0 = ni * 16 + 4 * lg;
      f32x4 bvv = *(const f32x4*)&bias[n0 + wn + d0];
#pragma unroll
      for (int mi = 0; mi < 4; ++mi) {
        const int s = m0 + wm + mi * 16 + lr;
        const int bI = s >> 10, srow = s & 1023;
        size_t addr = ((size_t)(bI * 8 + hI) << 16) + (srow >> 4) * 1024 +
                      (d0 >> 5) * 512 + ((d0 >> 3) & 3) * 128 + lr * 8 + (d0 & 7);
        ushort4_t pk;
#pragma unroll
        for (int r = 0; r < 4; ++r) pk[r] = f2bf(acc[ni][mi][r] + bvv[r]);
        *(ushort4_t*)&outp[addr] = pk;
      }
    }
  } else {
#pragma unroll
    for (int ni = 0; ni < 4; ++ni) {
      const float bv_ = bias[n0 + wn + ni * 16 + lr];
#pragma unroll
      for (int mi = 0; mi < 4; ++mi) {
        const int s0 = m0 + wm + mi * 16 + 4 * lg;
        const int bI = s0 >> 10, srow = s0 & 1023;
        size_t addr = ((size_t)(bI * 8 + hI) << 16) + (srow >> 6) * 4096 + ni * 1024 +
                      ((srow >> 5) & 1) * 512 + ((srow >> 3) & 3) * 128 + lr * 8 + (srow & 7);
        ushort4_t pk;
#pragma unroll
        for (int r = 0; r < 4; ++r) pk[r] = f2bf(acc[mi][ni][r] + bv_);
        *(ushort4_t*)&vt[addr] = pk;
      }
    }
  }
}

// Fused attention + out-proj epilogue, SINGLE-BUFFER sb (40.9KB total LDS ->
// 3 wgs/CU, 24 waves) for smoother nt-store duty cycle. 3 lgkm-only barriers
// per tile (top-of-loop WAR + B1 + B2). Main-loop math identical to R15.
__global__ __launch_bounds__(512, 6) void attn_fused(
    const unsigned short* __restrict__ qh, const unsigned short* __restrict__ kh,
    const unsigned short* __restrict__ vt, const int* __restrict__ mask,
    const unsigned short* __restrict__ wo16, const float* __restrict__ wo_b,
    float* __restrict__ attn_out, float* __restrict__ out) {
  __shared__ unsigned short sb[8][32][72];  // 36.9KB, logits->probs, single buffer
  __shared__ float mf[1024];                // -1e9 * mask[b][k]

  const int tid = threadIdx.x;
  const int h = tid >> 6, lane = tid & 63;
  const int lr = lane & 15, lg = lane >> 4;

  const int lin = blockIdx.x + 32 * blockIdx.y;
  const int xcd = lin & 7, slot = lin >> 3;
  const int b = xcd + 8 * (slot >> 5);
  const int q0 = (slot & 31) * 32;

  const unsigned short* qb = qh + ((size_t)(b * 8 + h) << 16);
  const unsigned short* kb = kh + ((size_t)(b * 8 + h) << 16);
  const unsigned short* vb = vt + ((size_t)(b * 8 + h) << 16);

#pragma unroll
  for (int i = 0; i < 2; ++i)
    mf[tid + i * 512] = -1e9f * (float)mask[b * 1024 + tid + i * 512];

  short8 qf[2][2];
#pragma unroll
  for (int qi = 0; qi < 2; ++qi)
#pragma unroll
    for (int ks = 0; ks < 2; ++ks)
      qf[qi][ks] = *(const short8*)(qb + ((q0 >> 4) + qi) * 1024 + ks * 512 + lane * 8);

  const int sq = tid >> 4, sk4 = tid & 15;

  f32x4 apv[2][4] = {};

  lds_barrier();  // mf visible

  for (int kt = 0; kt < 16; ++kt) {
    const int k0 = kt * 64;

    short8 kf[4][2];
#pragma unroll
    for (int ki = 0; ki < 4; ++ki)
#pragma unroll
      for (int ks = 0; ks < 2; ++ks)
        kf[ki][ks] = *(const short8*)(kb + ((k0 >> 4) + ki) * 1024 + ks * 512 + lane * 8);
    f32x4 aqk[4][2] = {};
#pragma unroll
    for (int ks = 0; ks < 2; ++ks)
#pragma unroll
      for (int ki = 0; ki < 4; ++ki)
#pragma unroll
        for (int qi = 0; qi < 2; ++qi)
          aqk[ki][qi] = MFMA16(kf[ki][ks], qf[qi][ks], aqk[ki][qi]);

    lds_barrier();  // B0: prev tile's PV reads of sb done (WAR)

#pragma unroll
    for (int ki = 0; ki < 4; ++ki) {
      f32x4 mv = *(const f32x4*)&mf[k0 + ki * 16 + 4 * lg];
#pragma unroll
      for (int qi = 0; qi < 2; ++qi) {
        ushort4_t pk;
#pragma unroll
        for (int r = 0; r < 4; ++r) pk[r] = f2bf(aqk[ki][qi][r] * 0.125f + mv[r]);
        *(ushort4_t*)&sb[h][qi * 16 + lr][ki * 16 + 4 * lg] = pk;
      }
    }

    short8 vf0[4];
#pragma unroll
    for (int ni = 0; ni < 4; ++ni)
      vf0[ni] = *(const short8*)(vb + kt * 4096 + ni * 1024 + lane * 8);

    lds_barrier();  // B1: logits visible

    f32x4 e[8];
#pragma unroll
    for (int hh = 0; hh < 8; ++hh) {
      ushort4_t raw = *(const ushort4_t*)&sb[hh][sq][4 * sk4];
#pragma unroll
      for (int r = 0; r < 4; ++r) e[hh][r] = bf2f(raw[r]);
    }
    f32x4 mx = e[0];
#pragma unroll
    for (int hh = 1; hh < 8; ++hh)
#pragma unroll
      for (int r = 0; r < 4; ++r) mx[r] = fmaxf(mx[r], e[hh][r]);
    f32x4 s = {0.f, 0.f, 0.f, 0.f};
#pragma unroll
    for (int hh = 0; hh < 8; ++hh) {
#pragma unroll
      for (int r = 0; r < 4; ++r) e[hh][r] = __expf(e[hh][r] - mx[r]);
      s += e[hh];
    }
    f32x4 inv;
#pragma unroll
    for (int r = 0; r < 4; ++r) inv[r] = __builtin_amdgcn_rcpf(s[r]);

    float* abase = attn_out + (((size_t)(b * 8) * 1024 + q0 + sq) * 1024) + k0 + 4 * sk4;
#pragma unroll
    for (int hh = 0; hh < 8; ++hh) {
      f32x4 p = e[hh] * inv;
      __builtin_nontemporal_store(p, (f32x4*)(abase + ((size_t)hh << 20)));
      ushort4_t pk;
#pragma unroll
      for (int r = 0; r < 4; ++r) pk[r] = f2bf(p[r]);
      *(ushort4_t*)&sb[hh][sq][4 * sk4] = pk;  // same-thread in-place rewrite
    }

    short8 vf1[4];
#pragma unroll
    for (int ni = 0; ni < 4; ++ni)
      vf1[ni] = *(const short8*)(vb + kt * 4096 + ni * 1024 + 512 + lane * 8);

    lds_barrier();  // B2: probs visible to PV

    short8 pf[2][2];
#pragma unroll
    for (int mi = 0; mi < 2; ++mi)
#pragma unroll
      for (int ks = 0; ks < 2; ++ks)
        pf[mi][ks] = *(const short8*)&sb[h][mi * 16 + lr][ks * 32 + 8 * lg];
#pragma unroll
    for (int mi = 0; mi < 2; ++mi)
#pragma unroll
      for (int ni = 0; ni < 4; ++ni)
        apv[mi][ni] = MFMA16(pf[mi][0], vf0[ni], apv[mi][ni]);
#pragma unroll
    for (int mi = 0; mi < 2; ++mi)
#pragma unroll
      for (int ni = 0; ni < 4; ++ni)
        apv[mi][ni] = MFMA16(pf[mi][1], vf1[ni], apv[mi][ni]);
  }

  // ---- OUT-PROJECTION epilogue (ctx slab through sb) ----
  lds_barrier();  // all waves' final PV reads done before slab overwrite (WAR)
  unsigned short* ctxs = &sb[0][0][0];  // [32][520] bf16 (33.3KB <= 36.9KB)
#pragma unroll
  for (int mi = 0; mi < 2; ++mi)
#pragma unroll
    for (int ni = 0; ni < 4; ++ni)
#pragma unroll
      for (int r = 0; r < 4; ++r) {
        const int row = mi * 16 + 4 * lg + r;
        const int col = h * 64 + ni * 16 + lr;
        ctxs[row * 520 + col] = f2bf(apv[mi][ni][r]);
      }
  lds_barrier();  // slab visible to all waves

  f32x4 acc2[4][2] = {};  // [ni2][mi2] (swapped)
#pragma unroll 4
  for (int ks = 0; ks < 16; ++ks) {
    short8 ctxf[2];
#pragma unroll
    for (int mi2 = 0; mi2 < 2; ++mi2)
      ctxf[mi2] = *(const short8*)&ctxs[(mi2 * 16 + lr) * 520 + ks * 32 + lg * 8];
    short8 wof[4];
#pragma unroll
    for (int ni2 = 0; ni2 < 4; ++ni2)
      wof[ni2] = *(const short8*)(wo16 + (size_t)(h * 4 + ni2) * 8192 + ks * 512 + lane * 8);
#pragma unroll
    for (int ni2 = 0; ni2 < 4; ++ni2)
#pragma unroll
      for (int mi2 = 0; mi2 < 2; ++mi2)
        acc2[ni2][mi2] = MFMA16(wof[ni2], ctxf[mi2], acc2[ni2][mi2]);
  }

#pragma unroll
  for (int ni2 = 0; ni2 < 4; ++ni2) {
    const int c0 = h * 64 + ni2 * 16 + 4 * lg;
    f32x4 bvv = *(const f32x4*)&wo_b[c0];
#pragma unroll
    for (int mi2 = 0; mi2 < 2; ++mi2) {
      const int rg = b * 1024 + q0 + mi2 * 16 + lr;
      f32x4 val = acc2[ni2][mi2] + bvv;
      *(f32x4*)&out[(size_t)rg * 512 + c0] = val;
    }
  }
}

extern "C" void kernel_launch(void* const* d_in, const int* in_sizes, int n_in,
                              void* d_out, int out_size, void* d_ws, size_t ws_size,
                              hipStream_t stream) {
  const float* q = (const float*)d_in[0];
  const float* k = (const float*)d_in[1];
  const float* v = (const float*)d_in[2];
  const int* mask = (const int*)d_in[3];
  const float* wq_w = (const float*)d_in[4];
  const float* wq_b = (const float*)d_in[5];
  const float* wk_w = (const float*)d_in[6];
  const float* wk_b = (const float*)d_in[7];
  const float* wv_w = (const float*)d_in[8];
  const float* wv_b = (const float*)d_in[9];
  const float* wo_w = (const float*)d_in[10];
  const float* wo_b = (const float*)d_in[11];

  float* out = (float*)d_out;                   // [16,1024,512]
  float* attn = out + (size_t)16 * 1024 * 512;  // [16,8,1024,1024] fp32

  // wq16/wk16/wv16: consumed by proj (before attn) -> attn-tail scratch.
  unsigned short* wq16 = (unsigned short*)(attn + (134217728 - 393216));
  unsigned short* wk16 = wq16 + 262144;
  unsigned short* wv16 = wk16 + 262144;

  unsigned short* qh = (unsigned short*)d_ws;              // frag-major [B,H][...]
  unsigned short* kh = qh + (size_t)16 * 8 * 1024 * 64;
  unsigned short* vt = kh + (size_t)16 * 8 * 1024 * 64;
  unsigned short* wo16 = vt + (size_t)16 * 8 * 1024 * 64;  // frag-major, read by attn

  cvt_w<<<dim3(512), dim3(256), 0, stream>>>(wq_w, wk_w, wv_w, wo_w,
                                             wq16, wk16, wv16, wo16);
  proj_gemm<<<dim3(128, 4, 3), dim3(256), 0, stream>>>(
      q, k, v, wq16, wk16, wv16, wq_b, wk_b, wv_b, qh, kh, vt);
  attn_fused<<<dim3(32, 16), dim3(512), 0, stream>>>(qh, kh, vt, mask, wo16, wo_b,
                                                     attn, out);
}

// Round 17
// 212.385 us; speedup vs baseline: 1.5733x; 1.5733x over previous
//
#include <hip/hip_runtime.h>
#include <hip/hip_bf16.h>
#include <math.h>

typedef __attribute__((ext_vector_type(8))) short short8;
typedef __attribute__((ext_vector_type(4))) float f32x4;
typedef __attribute__((ext_vector_type(4))) unsigned short ushort4_t;

#define MFMA16(a, b, c) __builtin_amdgcn_mfma_f32_16x16x32_bf16((a), (b), (c), 0, 0, 0)

#define GLOAD_LDS16(src, ldsbase)                                                     \
  __builtin_amdgcn_global_load_lds(                                                   \
      (const __attribute__((address_space(1))) void*)(src),                           \
      (__attribute__((address_space(3))) void*)(ldsbase), 16, 0, 0)

// Native RNE fp32->bf16 (compiler emits v_cvt_pk_bf16_f32 pairs).
static __device__ __forceinline__ unsigned short f2bf(float f) {
  __hip_bfloat16 h = __float2bfloat16(f);
  unsigned short u;
  __builtin_memcpy(&u, &h, 2);
  return u;
}

static __device__ __forceinline__ float bf2f(unsigned short b) {
  union { unsigned u; float f; } v; v.u = ((unsigned)b) << 16;
  return v.f;
}

static __device__ __forceinline__ short8 cvt2v(f32x4 a, f32x4 b) {
  short8 t;
#pragma unroll
  for (int j = 0; j < 4; ++j) t[j] = (short)f2bf(a[j]);
#pragma unroll
  for (int j = 0; j < 4; ++j) t[4 + j] = (short)f2bf(b[j]);
  return t;
}

// Barrier that waits only LDS (lgkmcnt), NOT vmcnt.
static __device__ __forceinline__ void lds_barrier() {
  __builtin_amdgcn_sched_barrier(0);
  asm volatile("s_waitcnt lgkmcnt(0)" ::: "memory");
  __builtin_amdgcn_s_barrier();
  __builtin_amdgcn_sched_barrier(0);
}

// fp32->bf16 weights. wq/wk/wv linear; wo FRAG-MAJOR for the attn epilogue.
__global__ __launch_bounds__(256) void cvt_w(
    const float* __restrict__ wq, const float* __restrict__ wk,
    const float* __restrict__ wv, const float* __restrict__ wo,
    unsigned short* __restrict__ wq16, unsigned short* __restrict__ wk16,
    unsigned short* __restrict__ wv16, unsigned short* __restrict__ wo16) {
  const int blk = blockIdx.x;
  const float* src;
  unsigned short* dst;
  size_t base;
  bool frag = false;
  if (blk < 128)      { src = wq; dst = wq16; base = (size_t)blk * 2048; }
  else if (blk < 256) { src = wk; dst = wk16; base = (size_t)(blk - 128) * 2048; }
  else if (blk < 384) { src = wv; dst = wv16; base = (size_t)(blk - 256) * 2048; }
  else                { src = wo; dst = wo16; base = (size_t)(blk - 384) * 2048; frag = true; }
  const size_t i = base + (size_t)threadIdx.x * 8;
  f32x4 a = *(const f32x4*)(src + i);
  f32x4 b = *(const f32x4*)(src + i + 4);
  if (!frag) {
    *(short8*)(dst + i) = cvt2v(a, b);
  } else {
    const int c = (int)(i >> 9), k = (int)(i & 511);
    size_t addr = (size_t)(c >> 4) * 8192 + (k >> 5) * 512 + ((k >> 3) & 3) * 128 +
                  (c & 15) * 8 + (k & 7);
    *(short8*)(dst + addr) = cvt2v(a, b);
  }
}

// Merged QKV projection, z=0/1/2. A fp32 reg-staged->bf16 LDS; W bf16 DMA.
__global__ __launch_bounds__(256) void proj_gemm(
    const float* __restrict__ q, const float* __restrict__ k, const float* __restrict__ v,
    const unsigned short* __restrict__ wq16, const unsigned short* __restrict__ wk16,
    const unsigned short* __restrict__ wv16,
    const float* __restrict__ bq, const float* __restrict__ bk, const float* __restrict__ bv,
    unsigned short* __restrict__ qh, unsigned short* __restrict__ kh,
    unsigned short* __restrict__ vt) {
  __shared__ unsigned short As[128 * 64], Ws[128 * 64];
  const int z = blockIdx.z;
  const float* A = z == 0 ? q : z == 1 ? k : v;
  const unsigned short* W16 = z == 0 ? wq16 : z == 1 ? wk16 : wv16;
  const float* bias = z == 0 ? bq : z == 1 ? bk : bv;
  unsigned short* outp = z == 0 ? qh : z == 1 ? kh : vt;

  const int tid = threadIdx.x;
  const int wv_ = tid >> 6, lane = tid & 63;
  const int lr = lane & 15, lg = lane >> 4;
  const int m0 = blockIdx.x * 128, n0 = blockIdx.y * 128;
  const int wm = (wv_ >> 1) * 64, wn = (wv_ & 1) * 64;

  f32x4 acc[4][4] = {};  // z<2: [ni][mi]; z==2: [mi][ni]

  for (int k0 = 0; k0 < 512; k0 += 64) {
#pragma unroll
    for (int p = 0; p < 4; ++p) {
      const int row = (p * 4 + wv_) * 8 + (lane >> 3);
      const int col = (lane & 7) * 8;
      GLOAD_LDS16(W16 + (size_t)(n0 + row) * 512 + k0 + col, &Ws[(p * 4 + wv_) * 512]);
    }
    const int row = (tid >> 3), col = (tid & 7) * 8;
#pragma unroll
    for (int p = 0; p < 4; ++p) {
      const float* src = A + (size_t)(m0 + p * 32 + row) * 512 + k0 + col;
      f32x4 a0 = *(const f32x4*)src;
      f32x4 a1 = *(const f32x4*)(src + 4);
      *(short8*)&As[(p * 32 + row) * 64 + col] = cvt2v(a0, a1);
    }
    __syncthreads();  // drains vmcnt (gload_lds) + lgkmcnt (ds_write)

#pragma unroll
    for (int ks = 0; ks < 2; ++ks) {
      short8 af[4], bw[4];
#pragma unroll
      for (int mi = 0; mi < 4; ++mi)
        af[mi] = *(const short8*)&As[(wm + mi * 16 + lr) * 64 + ks * 32 + lg * 8];
#pragma unroll
      for (int ni = 0; ni < 4; ++ni)
        bw[ni] = *(const short8*)&Ws[(wn + ni * 16 + lr) * 64 + ks * 32 + lg * 8];
      if (z < 2) {
#pragma unroll
        for (int ni = 0; ni < 4; ++ni)
#pragma unroll
          for (int mi = 0; mi < 4; ++mi)
            acc[ni][mi] = MFMA16(bw[ni], af[mi], acc[ni][mi]);  // swapped
      } else {
#pragma unroll
        for (int mi = 0; mi < 4; ++mi)
#pragma unroll
          for (int ni = 0; ni < 4; ++ni)
            acc[mi][ni] = MFMA16(af[mi], bw[ni], acc[mi][ni]);
      }
    }
    __syncthreads();
  }

  const int hI = (n0 + wn) >> 6;
  if (z < 2) {
#pragma unroll
    for (int ni = 0; ni < 4; ++ni) {
      const int d0 = ni * 16 + 4 * lg;
      f32x4 bvv = *(const f32x4*)&bias[n0 + wn + d0];
#pragma unroll
      for (int mi = 0; mi < 4; ++mi) {
        const int s = m0 + wm + mi * 16 + lr;
        const int bI = s >> 10, srow = s & 1023;
        size_t addr = ((size_t)(bI * 8 + hI) << 16) + (srow >> 4) * 1024 +
                      (d0 >> 5) * 512 + ((d0 >> 3) & 3) * 128 + lr * 8 + (d0 & 7);
        ushort4_t pk;
#pragma unroll
        for (int r = 0; r < 4; ++r) pk[r] = f2bf(acc[ni][mi][r] + bvv[r]);
        *(ushort4_t*)&outp[addr] = pk;
      }
    }
  } else {
#pragma unroll
    for (int ni = 0; ni < 4; ++ni) {
      const float bv_ = bias[n0 + wn + ni * 16 + lr];
#pragma unroll
      for (int mi = 0; mi < 4; ++mi) {
        const int s0 = m0 + wm + mi * 16 + 4 * lg;
        const int bI = s0 >> 10, srow = s0 & 1023;
        size_t addr = ((size_t)(bI * 8 + hI) << 16) + (srow >> 6) * 4096 + ni * 1024 +
                      ((srow >> 5) & 1) * 512 + ((srow >> 3) & 3) * 128 + lr * 8 + (srow & 7);
        ushort4_t pk;
#pragma unroll
        for (int r = 0; r < 4; ++r) pk[r] = f2bf(acc[mi][ni][r] + bv_);
        *(ushort4_t*)&vt[addr] = pk;
      }
    }
  }
}

// Fused attention + OUT-PROJECTION epilogue (R15 verbatim: dbuf sb, 2 wgs/CU).
__global__ __launch_bounds__(512, 4) void attn_fused(
    const unsigned short* __restrict__ qh, const unsigned short* __restrict__ kh,
    const unsigned short* __restrict__ vt, const int* __restrict__ mask,
    const unsigned short* __restrict__ wo16, const float* __restrict__ wo_b,
    float* __restrict__ attn_out, float* __restrict__ out) {
  __shared__ unsigned short sb[2][8][32][72];  // logits->probs dbuf; sb[0] reused as ctx slab
  __shared__ float mf[1024];                   // -1e9 * mask[b][k]

  const int tid = threadIdx.x;
  const int h = tid >> 6, lane = tid & 63;
  const int lr = lane & 15, lg = lane >> 4;

  const int lin = blockIdx.x + 32 * blockIdx.y;
  const int xcd = lin & 7, slot = lin >> 3;
  const int b = xcd + 8 * (slot >> 5);
  const int q0 = (slot & 31) * 32;

  const unsigned short* qb = qh + ((size_t)(b * 8 + h) << 16);
  const unsigned short* kb = kh + ((size_t)(b * 8 + h) << 16);
  const unsigned short* vb = vt + ((size_t)(b * 8 + h) << 16);

#pragma unroll
  for (int i = 0; i < 2; ++i)
    mf[tid + i * 512] = -1e9f * (float)mask[b * 1024 + tid + i * 512];

  short8 qf[2][2];
#pragma unroll
  for (int qi = 0; qi < 2; ++qi)
#pragma unroll
    for (int ks = 0; ks < 2; ++ks)
      qf[qi][ks] = *(const short8*)(qb + ((q0 >> 4) + qi) * 1024 + ks * 512 + lane * 8);

  const int sq = tid >> 4, sk4 = tid & 15;

  f32x4 apv[2][4] = {};

  lds_barrier();  // mf visible

  for (int kt = 0; kt < 16; ++kt) {
    const int k0 = kt * 64;
    unsigned short(*sc)[32][72] = sb[kt & 1];

    short8 kf[4][2];
#pragma unroll
    for (int ki = 0; ki < 4; ++ki)
#pragma unroll
      for (int ks = 0; ks < 2; ++ks)
        kf[ki][ks] = *(const short8*)(kb + ((k0 >> 4) + ki) * 1024 + ks * 512 + lane * 8);
    f32x4 aqk[4][2] = {};
#pragma unroll
    for (int ks = 0; ks < 2; ++ks)
#pragma unroll
      for (int ki = 0; ki < 4; ++ki)
#pragma unroll
        for (int qi = 0; qi < 2; ++qi)
          aqk[ki][qi] = MFMA16(kf[ki][ks], qf[qi][ks], aqk[ki][qi]);

#pragma unroll
    for (int ki = 0; ki < 4; ++ki) {
      f32x4 mv = *(const f32x4*)&mf[k0 + ki * 16 + 4 * lg];
#pragma unroll
      for (int qi = 0; qi < 2; ++qi) {
        ushort4_t pk;
#pragma unroll
        for (int r = 0; r < 4; ++r) pk[r] = f2bf(aqk[ki][qi][r] * 0.125f + mv[r]);
        *(ushort4_t*)&sc[h][qi * 16 + lr][ki * 16 + 4 * lg] = pk;
      }
    }

    short8 vf0[4];
#pragma unroll
    for (int ni = 0; ni < 4; ++ni)
      vf0[ni] = *(const short8*)(vb + kt * 4096 + ni * 1024 + lane * 8);

    lds_barrier();  // B1

    f32x4 e[8];
#pragma unroll
    for (int hh = 0; hh < 8; ++hh) {
      ushort4_t raw = *(const ushort4_t*)&sc[hh][sq][4 * sk4];
#pragma unroll
      for (int r = 0; r < 4; ++r) e[hh][r] = bf2f(raw[r]);
    }
    f32x4 mx = e[0];
#pragma unroll
    for (int hh = 1; hh < 8; ++hh)
#pragma unroll
      for (int r = 0; r < 4; ++r) mx[r] = fmaxf(mx[r], e[hh][r]);
    f32x4 s = {0.f, 0.f, 0.f, 0.f};
#pragma unroll
    for (int hh = 0; hh < 8; ++hh) {
#pragma unroll
      for (int r = 0; r < 4; ++r) e[hh][r] = __expf(e[hh][r] - mx[r]);
      s += e[hh];
    }
    f32x4 inv;
#pragma unroll
    for (int r = 0; r < 4; ++r) inv[r] = __builtin_amdgcn_rcpf(s[r]);

    float* abase = attn_out + (((size_t)(b * 8) * 1024 + q0 + sq) * 1024) + k0 + 4 * sk4;
#pragma unroll
    for (int hh = 0; hh < 8; ++hh) {
      f32x4 p = e[hh] * inv;
      __builtin_nontemporal_store(p, (f32x4*)(abase + ((size_t)hh << 20)));
      ushort4_t pk;
#pragma unroll
      for (int r = 0; r < 4; ++r) pk[r] = f2bf(p[r]);
      *(ushort4_t*)&sc[hh][sq][4 * sk4] = pk;
    }

    short8 vf1[4];
#pragma unroll
    for (int ni = 0; ni < 4; ++ni)
      vf1[ni] = *(const short8*)(vb + kt * 4096 + ni * 1024 + 512 + lane * 8);

    lds_barrier();  // B2

    short8 pf[2][2];
#pragma unroll
    for (int mi = 0; mi < 2; ++mi)
#pragma unroll
      for (int ks = 0; ks < 2; ++ks)
        pf[mi][ks] = *(const short8*)&sc[h][mi * 16 + lr][ks * 32 + 8 * lg];
#pragma unroll
    for (int mi = 0; mi < 2; ++mi)
#pragma unroll
      for (int ni = 0; ni < 4; ++ni)
        apv[mi][ni] = MFMA16(pf[mi][0], vf0[ni], apv[mi][ni]);
#pragma unroll
    for (int mi = 0; mi < 2; ++mi)
#pragma unroll
      for (int ni = 0; ni < 4; ++ni)
        apv[mi][ni] = MFMA16(pf[mi][1], vf1[ni], apv[mi][ni]);
  }

  // ---- OUT-PROJECTION epilogue ----
  unsigned short* ctxs = &sb[0][0][0][0];  // [32][520] bf16 (33.3KB)
#pragma unroll
  for (int mi = 0; mi < 2; ++mi)
#pragma unroll
    for (int ni = 0; ni < 4; ++ni)
#pragma unroll
      for (int r = 0; r < 4; ++r) {
        const int row = mi * 16 + 4 * lg + r;
        const int col = h * 64 + ni * 16 + lr;
        ctxs[row * 520 + col] = f2bf(apv[mi][ni][r]);
      }
  lds_barrier();  // slab visible to all waves

  f32x4 acc2[4][2] = {};  // [ni2][mi2] (swapped)
#pragma unroll 4
  for (int ks = 0; ks < 16; ++ks) {
    short8 ctxf[2];
#pragma unroll
    for (int mi2 = 0; mi2 < 2; ++mi2)
      ctxf[mi2] = *(const short8*)&ctxs[(mi2 * 16 + lr) * 520 + ks * 32 + lg * 8];
    short8 wof[4];
#pragma unroll
    for (int ni2 = 0; ni2 < 4; ++ni2)
      wof[ni2] = *(const short8*)(wo16 + (size_t)(h * 4 + ni2) * 8192 + ks * 512 + lane * 8);
#pragma unroll
    for (int ni2 = 0; ni2 < 4; ++ni2)
#pragma unroll
      for (int mi2 = 0; mi2 < 2; ++mi2)
        acc2[ni2][mi2] = MFMA16(wof[ni2], ctxf[mi2], acc2[ni2][mi2]);
  }

#pragma unroll
  for (int ni2 = 0; ni2 < 4; ++ni2) {
    const int c0 = h * 64 + ni2 * 16 + 4 * lg;
    f32x4 bvv = *(const f32x4*)&wo_b[c0];
#pragma unroll
    for (int mi2 = 0; mi2 < 2; ++mi2) {
      const int rg = b * 1024 + q0 + mi2 * 16 + lr;
      f32x4 val = acc2[ni2][mi2] + bvv;
      *(f32x4*)&out[(size_t)rg * 512 + c0] = val;
    }
  }
}

extern "C" void kernel_launch(void* const* d_in, const int* in_sizes, int n_in,
                              void* d_out, int out_size, void* d_ws, size_t ws_size,
                              hipStream_t stream) {
  const float* q = (const float*)d_in[0];
  const float* k = (const float*)d_in[1];
  const float* v = (const float*)d_in[2];
  const int* mask = (const int*)d_in[3];
  const float* wq_w = (const float*)d_in[4];
  const float* wq_b = (const float*)d_in[5];
  const float* wk_w = (const float*)d_in[6];
  const float* wk_b = (const float*)d_in[7];
  const float* wv_w = (const float*)d_in[8];
  const float* wv_b = (const float*)d_in[9];
  const float* wo_w = (const float*)d_in[10];
  const float* wo_b = (const float*)d_in[11];

  float* out = (float*)d_out;                   // [16,1024,512]
  float* attn = out + (size_t)16 * 1024 * 512;  // [16,8,1024,1024] fp32

  // wq16/wk16/wv16: consumed by proj (before attn) -> attn-tail scratch.
  unsigned short* wq16 = (unsigned short*)(attn + (134217728 - 393216));
  unsigned short* wk16 = wq16 + 262144;
  unsigned short* wv16 = wk16 + 262144;

  unsigned short* qh = (unsigned short*)d_ws;              // frag-major [B,H][...]
  unsigned short* kh = qh + (size_t)16 * 8 * 1024 * 64;
  unsigned short* vt = kh + (size_t)16 * 8 * 1024 * 64;
  unsigned short* wo16 = vt + (size_t)16 * 8 * 1024 * 64;  // frag-major, read by attn

  cvt_w<<<dim3(512), dim3(256), 0, stream>>>(wq_w, wk_w, wv_w, wo_w,
                                             wq16, wk16, wv16, wo16);
  proj_gemm<<<dim3(128, 4, 3), dim3(256), 0, stream>>>(
      q, k, v, wq16, wk16, wv16, wq_b, wk_b, wv_b, qh, kh, vt);
  attn_fused<<<dim3(32, 16), dim3(512), 0, stream>>>(qh, kh, vt, mask, wo16, wo_b,
                                                     attn, out);
}